// Round 7
// baseline (104.835 us; speedup 1.0000x reference)
//
#include <hip/hip_runtime.h>
#include <math.h>

#define EMB 512
#define NM 5
#define HID 64
#define NQ 2048
#define NP 256

typedef __attribute__((ext_vector_type(8))) short short8;   // 8 bf16 = 16B
typedef __attribute__((ext_vector_type(4))) short short4s;  // 4 bf16 = 8B
typedef __attribute__((ext_vector_type(4))) float floatx4;
typedef __attribute__((ext_vector_type(4))) float vf4;
typedef __attribute__((ext_vector_type(2))) float vf2;

// ws layout (bytes)
#define A_BY  0u                   // A[m][q][h] f32 (+b1)          2,621,440
#define B_BY  2621440u             // B[m][h/4][p][h%4] f32           327,680
#define WH_BY 2949120u             // W1 hi bf16 [5][64][1024]        655,360
#define WL_BY 3604480u             // W1 lo bf16 [5][64][1024]        655,360
#define QH_BY 4259840u             // Q  hi bf16 [2048][512]        2,097,152
#define PH_BY 6356992u             // P  hi bf16 [256][512]           262,144

__device__ inline unsigned short bfr(float f) {            // f32 -> bf16 RNE
    unsigned u = __float_as_uint(f);
    u += 0x7FFFu + ((u >> 16) & 1u);
    return (unsigned short)(u >> 16);
}

// ---------------------------------------------------------------------------
// Kernel 0: one-shot conversion — UNCHANGED (bit-identical bfr math; gemm
// preserves MFMA order -> absmax stays 0.0009765625 exactly).
__global__ __launch_bounds__(256) void cvt_pre(const float* __restrict__ Q,
                                               const float* __restrict__ P,
                                               const float* __restrict__ W1,
                                               short* __restrict__ WHg,
                                               short* __restrict__ WLg,
                                               short* __restrict__ QHg,
                                               short* __restrict__ PHg) {
    int i = blockIdx.x * 256 + threadIdx.x;
    if (i < 81920) {
        float4 v = ((const float4*)W1)[i];
        short4s hi, lo;
#define C1(I, V) { unsigned short h_ = bfr(V); hi[I] = (short)h_; \
    lo[I] = (short)bfr((V) - __uint_as_float(((unsigned)h_) << 16)); }
        C1(0, v.x) C1(1, v.y) C1(2, v.z) C1(3, v.w)
#undef C1
        ((short4s*)WHg)[i] = hi;
        ((short4s*)WLg)[i] = lo;
    } else if (i < 81920 + 262144) {
        int j = i - 81920;
        float4 v = ((const float4*)Q)[j];
        short4s hi;
        hi[0] = (short)bfr(v.x); hi[1] = (short)bfr(v.y);
        hi[2] = (short)bfr(v.z); hi[3] = (short)bfr(v.w);
        ((short4s*)QHg)[j] = hi;
    } else {
        int j = i - 344064;
        float4 v = ((const float4*)P)[j];
        short4s hi;
        hi[0] = (short)bfr(v.x); hi[1] = (short)bfr(v.y);
        hi[2] = (short)bfr(v.z); hi[3] = (short)bfr(v.w);
        ((short4s*)PHg)[j] = hi;
    }
}

// ---------------------------------------------------------------------------
// Kernel 1: gemm_v5 — R6 discriminating experiment: BARRIER-FREE, LDS-FREE.
// R6 algebra says gemm phase ~30 us (10x over its ~3 us model); prime suspect
// is the per-chunk s_waitcnt vmcnt(0)+s_barrier drain (hipcc emits it before
// every __syncthreads, defeating the prefetch). This version: each wave owns
// one 16-row x 16-h tile, loads A/B fragments DIRECTLY from L2-resident
// pre-converted bf16 (per k-step 3x global_load_dwordx4; same lane->element
// mapping as the LDS reads: row=lane&15, k+=(lane>>4)*8). No __syncthreads
// anywhere; 16 unrolled independent k-steps -> compiler clusters loads with
// counted vmcnt. Same k order + same mfma sequence -> bit-identical result.
__global__ __launch_bounds__(256) void gemm_v5(const short* __restrict__ WHg,
                                               const short* __restrict__ WLg,
                                               const short* __restrict__ QHg,
                                               const short* __restrict__ PHg,
                                               const float* __restrict__ b1,
                                               float* __restrict__ A,
                                               float* __restrict__ Bv) {
    int tid  = threadIdx.x;
    int lane = tid & 63;
    int ht   = tid >> 6;                 // 0..3: h-subtile
    int m    = blockIdx.x % 5;
    int rt   = blockIdx.x / 5;           // 0..143
    int r0   = rt * 16;
    bool isQ = rt < 128;
    int off  = isQ ? 0 : 512;

    int lr = lane & 15;                  // fragment row
    int lk = (lane >> 4) * 8;            // fragment k-offset (shorts)

    const short* xp = (isQ ? QHg + (size_t)(r0 + lr) * 512
                           : PHg + (size_t)(r0 - NQ + lr) * 512) + lk;
    const short* wh = WHg + ((size_t)(m * 64 + ht * 16 + lr)) * 1024 + off + lk;
    const short* wl = WLg + ((size_t)(m * 64 + ht * 16 + lr)) * 1024 + off + lk;

    floatx4 ac = {0, 0, 0, 0};

#pragma unroll
    for (int t = 0; t < 16; ++t) {       // k = t*32, ascending (order preserved)
        short8 Ah = *(const short8*)&xp[t * 32];
        short8 Bh = *(const short8*)&wh[t * 32];
        short8 Bl = *(const short8*)&wl[t * 32];
        ac = __builtin_amdgcn_mfma_f32_16x16x32_bf16(Ah, Bl, ac, 0, 0, 0);
        ac = __builtin_amdgcn_mfma_f32_16x16x32_bf16(Ah, Bh, ac, 0, 0, 0);
    }

    int col  = lane & 15;
    int rloc = (lane >> 4) * 4;
    int hh   = ht * 16 + col;
    int rr   = r0 + rloc;

    if (isQ) {
        float bb = b1[m * 64 + hh];
        float* dst = &A[((size_t)m * NQ + rr) * HID + hh];
        dst[0 * HID] = ac.x + bb; dst[1 * HID] = ac.y + bb;
        dst[2 * HID] = ac.z + bb; dst[3 * HID] = ac.w + bb;
    } else {
        int p = rr - NQ;
        float* dst = &Bv[(((size_t)(m * 16 + (hh >> 2))) * NP + p) * 4 + (hh & 3)];
        dst[0 * 4] = ac.x; dst[1 * 4] = ac.y; dst[2 * 4] = ac.z; dst[3 * 4] = ac.w;
    }
}

// ---------------------------------------------------------------------------
// Kernel 2: fused relu-ensemble + mean/std/exp — UNCHANGED (verified ~21 us
// anchor: grid 1024, 4 blocks/CU, A in LDS stride-68, single Bc[16], pk-f32).
#define AST 68
__global__ __launch_bounds__(256) void fused_main(const float* __restrict__ A,
                                                  const float* __restrict__ Bv,
                                                  const float* __restrict__ W2,
                                                  const float* __restrict__ b2,
                                                  float* __restrict__ out) {
    __shared__ float As[NM][8][AST];          // 10,880 B

    int tid  = threadIdx.x;
    int bp   = (blockIdx.x & 3) * 64;         // p-tile base
    int q0   = (blockIdx.x >> 2) * 8;         // q-tile base
    int p    = tid >> 2;                      // 0..63 within p-tile
    int qg   = tid & 3;                       // 0..3

    {
        const float4* Ag = (const float4*)A;  // f4 idx (m*NQ+q)*16 + j
        for (int i = tid; i < 640; i += 256) {
            int m = i >> 7, rem = i & 127;
            int qr = rem >> 4, j = rem & 15;
            *(float4*)&As[m][qr][j * 4] =
                Ag[(size_t)m * (NQ * 16) + (size_t)(q0 + qr) * 16 + j];
        }
    }
    __syncthreads();

    const vf4* Bq = (const vf4*)Bv + (bp + p);   // f4 idx (m*16+j)*NP + p

    float s1[2] = {0.f, 0.f}, s2[2] = {0.f, 0.f};

#pragma unroll 1
    for (int m = 0; m < NM; ++m) {
        vf4 Bc[16];
#pragma unroll
        for (int j = 0; j < 16; ++j) Bc[j] = Bq[(m * 16 + j) * NP];

        const float* Wm = W2 + m * HID;           // block-uniform
        float bb = b2[m];

#pragma unroll
        for (int qi = 0; qi < 2; ++qi) {
            const float* Ar = &As[m][qg * 2 + qi][0];
            vf2 acc = {0.f, 0.f};
#pragma unroll
            for (int j = 0; j < 16; ++j) {
                vf2 a0 = *(const vf2*)&Ar[j * 4 + 0];
                vf2 a1 = *(const vf2*)&Ar[j * 4 + 2];
                vf2 w0 = *(const vf2*)&Wm[j * 4 + 0];
                vf2 w1 = *(const vf2*)&Wm[j * 4 + 2];
                vf2 z  = {0.f, 0.f};
                vf2 t0 = __builtin_elementwise_max(a0 + Bc[j].xy, z);
                vf2 t1 = __builtin_elementwise_max(a1 + Bc[j].zw, z);
                acc = t0 * w0 + acc;              // v_pk_fma_f32
                acc = t1 * w1 + acc;
            }
            float x = acc.x + acc.y + bb;
            s1[qi] += x;
            s2[qi] = fmaf(x, x, s2[qi]);
        }
    }

#pragma unroll
    for (int qi = 0; qi < 2; ++qi) {
        float mean = s1[qi] * 0.2f;
        float var  = fmaxf((s2[qi] - s1[qi] * s1[qi] * 0.2f) * 0.25f, 0.f);
        out[(size_t)(q0 + qg * 2 + qi) * NP + bp + p] =
            mean * __expf(-sqrtf(var));
    }
}

// ---------------------------------------------------------------------------
extern "C" void kernel_launch(void* const* d_in, const int* in_sizes, int n_in,
                              void* d_out, int out_size, void* d_ws, size_t ws_size,
                              hipStream_t stream) {
    const float* Q  = (const float*)d_in[0];   // (2048, 512)
    const float* P  = (const float*)d_in[1];   // (256, 512)
    const float* W1 = (const float*)d_in[2];   // (5, 64, 1024)
    const float* b1 = (const float*)d_in[3];   // (5, 64)
    const float* W2 = (const float*)d_in[4];   // (5, 64)
    const float* b2 = (const float*)d_in[5];   // (5,)
    float* out = (float*)d_out;

    char*  ws  = (char*)d_ws;
    float* A   = (float*)(ws + A_BY);
    float* B   = (float*)(ws + B_BY);
    short* WHg = (short*)(ws + WH_BY);
    short* WLg = (short*)(ws + WL_BY);
    short* QHg = (short*)(ws + QH_BY);
    short* PHg = (short*)(ws + PH_BY);

    cvt_pre<<<1472, 256, 0, stream>>>(Q, P, W1, WHg, WLg, QHg, PHg);
    gemm_v5<<<720, 256, 0, stream>>>(WHg, WLg, QHg, PHg, b1, A, B);
    fused_main<<<1024, 256, 0, stream>>>(A, B, W2, b2, out);
}